// Round 1
// baseline (679.335 us; speedup 1.0000x reference)
//
#include <hip/hip_runtime.h>
#include <math.h>

// Attention_28200755265553: B=64,T=128,S=1024,IN=OUT=1024,CAT=2048
// Inputs: dec[64,128,1024]f32, enc[64,1024,1024]f32, mask[64,1024]int,
//         W_attn[1024,1024]f32, W_out[1024,2048]f32, b_out[1024]f32
// Outputs (concat): attn_outputs[64,128,1024]f32, attn_weights[64,128,1024]f32

#define LSTR 40  // LDS row stride in ushorts: 32 + 8 pad, keeps 16B alignment (80B rows)

typedef __attribute__((ext_vector_type(8))) short short8;
typedef __attribute__((ext_vector_type(4))) float f32x4;
typedef __attribute__((ext_vector_type(4))) unsigned short u16x4;

__device__ __forceinline__ unsigned short f2bf(float x) {
    union { float f; unsigned int u; } v; v.f = x;
    unsigned int u = v.u + (0x7fffu + ((v.u >> 16) & 1u)); // RNE
    return (unsigned short)(u >> 16);
}
__device__ __forceinline__ float bf2f(unsigned short h) {
    union { unsigned int u; float f; } v; v.u = ((unsigned int)h) << 16;
    return v.f;
}

// ---------------------------------------------------------------------------
// C = A @ B^T with on-the-fly fp32 -> (hi,lo) bf16 split, fp32-accurate result.
// A [.,K] row-major lda=K; B [N,K] row-major ldb=K; C ldc=N. 128x128 tile/block.
// Used for q_proj (grid 64,8,1) and scores (grid 1,8,64 with batch strides).
// ---------------------------------------------------------------------------
__global__ __launch_bounds__(256) void gemm_bt_split(
    const float* __restrict__ A, const float* __restrict__ B, float* __restrict__ C,
    int N, int K, long long sA, long long sB, long long sC)
{
    const float* Ab = A + blockIdx.z * sA;
    const float* Bb = B + blockIdx.z * sB;
    float*       Cb = C + blockIdx.z * sC;
    const int m0 = blockIdx.x * 128, n0 = blockIdx.y * 128;

    __shared__ unsigned short Ah[128*LSTR], Al[128*LSTR], Bh[128*LSTR], Bl[128*LSTR];

    const int tid = threadIdx.x;
    const int lane = tid & 63, wave = tid >> 6;
    const int wm = (wave & 1) * 64, wn = (wave >> 1) * 64;
    const int fr = lane & 15, kq = lane >> 4;

    f32x4 zero = {0.f, 0.f, 0.f, 0.f};
    f32x4 acc[4][4];
    #pragma unroll
    for (int i = 0; i < 4; i++)
        #pragma unroll
        for (int j = 0; j < 4; j++) acc[i][j] = zero;

    for (int k0 = 0; k0 < K; k0 += 32) {
        #pragma unroll
        for (int i = 0; i < 4; i++) {
            int f = i * 256 + tid;          // float4 id 0..1023 (128 rows x 8 f4)
            int row = f >> 3, c4 = (f & 7) * 4;
            float4 a4 = *(const float4*)(Ab + (long long)(m0 + row) * K + k0 + c4);
            float4 b4 = *(const float4*)(Bb + (long long)(n0 + row) * K + k0 + c4);
            float av[4] = {a4.x, a4.y, a4.z, a4.w};
            float bv[4] = {b4.x, b4.y, b4.z, b4.w};
            u16x4 ah, al, bh, bl;
            #pragma unroll
            for (int j = 0; j < 4; j++) {
                unsigned short h = f2bf(av[j]);
                ah[j] = h; al[j] = f2bf(av[j] - bf2f(h));
                h = f2bf(bv[j]);
                bh[j] = h; bl[j] = f2bf(bv[j] - bf2f(h));
            }
            *(u16x4*)&Ah[row*LSTR + c4] = ah;
            *(u16x4*)&Al[row*LSTR + c4] = al;
            *(u16x4*)&Bh[row*LSTR + c4] = bh;
            *(u16x4*)&Bl[row*LSTR + c4] = bl;
        }
        __syncthreads();

        short8 fah[4], fal[4], fbh[4], fbl[4];
        #pragma unroll
        for (int fi = 0; fi < 4; fi++) {
            fah[fi] = *(const short8*)&Ah[(wm + fi*16 + fr)*LSTR + kq*8];
            fal[fi] = *(const short8*)&Al[(wm + fi*16 + fr)*LSTR + kq*8];
            fbh[fi] = *(const short8*)&Bh[(wn + fi*16 + fr)*LSTR + kq*8];
            fbl[fi] = *(const short8*)&Bl[(wn + fi*16 + fr)*LSTR + kq*8];
        }
        #pragma unroll
        for (int fi = 0; fi < 4; fi++)
            #pragma unroll
            for (int fj = 0; fj < 4; fj++) {
                acc[fi][fj] = __builtin_amdgcn_mfma_f32_16x16x32_bf16(fah[fi], fbh[fj], acc[fi][fj], 0, 0, 0);
                acc[fi][fj] = __builtin_amdgcn_mfma_f32_16x16x32_bf16(fah[fi], fbl[fj], acc[fi][fj], 0, 0, 0);
                acc[fi][fj] = __builtin_amdgcn_mfma_f32_16x16x32_bf16(fal[fi], fbh[fj], acc[fi][fj], 0, 0, 0);
            }
        __syncthreads();
    }

    #pragma unroll
    for (int fi = 0; fi < 4; fi++) {
        int rb = m0 + wm + fi*16 + kq*4;
        #pragma unroll
        for (int fj = 0; fj < 4; fj++) {
            int col = n0 + wn + fj*16 + fr;
            #pragma unroll
            for (int j = 0; j < 4; j++)
                Cb[(long long)(rb + j) * N + col] = acc[fi][fj][j];
        }
    }
}

// ---------------------------------------------------------------------------
// Masked softmax over S=1024, in place on the scores buffer (= d_out weights
// region); also emits a bf16 copy of the weights for the context GEMM.
// One block (256 thr) per row; 4 contiguous elems/thread.
// ---------------------------------------------------------------------------
__global__ __launch_bounds__(256) void softmax_mask(
    float* __restrict__ sw, const int* __restrict__ mask,
    unsigned short* __restrict__ wbf)
{
    const int row = blockIdx.x;          // 0..8191 = b*128 + t
    const int b = row >> 7;
    const int tid = threadIdx.x, lane = tid & 63, wave = tid >> 6;
    float* sr = sw + (long long)row * 1024;
    const int* mr = mask + (long long)b * 1024;

    float4 x = *(const float4*)(sr + tid * 4);
    int4  mk = *(const int4*)(mr + tid * 4);
    float v0 = mk.x ? -INFINITY : x.x;
    float v1 = mk.y ? -INFINITY : x.y;
    float v2 = mk.z ? -INFINITY : x.z;
    float v3 = mk.w ? -INFINITY : x.w;

    float mx = fmaxf(fmaxf(v0, v1), fmaxf(v2, v3));
    #pragma unroll
    for (int off = 32; off; off >>= 1) mx = fmaxf(mx, __shfl_xor(mx, off));
    __shared__ float redm[4];
    __shared__ float reds[4];
    if (lane == 0) redm[wave] = mx;
    __syncthreads();
    mx = fmaxf(fmaxf(redm[0], redm[1]), fmaxf(redm[2], redm[3]));

    float p0 = __expf(v0 - mx), p1 = __expf(v1 - mx);
    float p2 = __expf(v2 - mx), p3 = __expf(v3 - mx);
    float s = (p0 + p1) + (p2 + p3);
    #pragma unroll
    for (int off = 32; off; off >>= 1) s += __shfl_xor(s, off);
    if (lane == 0) reds[wave] = s;
    __syncthreads();
    s = (reds[0] + reds[1]) + (reds[2] + reds[3]);
    float inv = 1.0f / s;

    float w0 = p0*inv, w1 = p1*inv, w2 = p2*inv, w3 = p3*inv;
    float4 w4; w4.x = w0; w4.y = w1; w4.z = w2; w4.w = w3;
    *(float4*)(sr + tid * 4) = w4;
    u16x4 wb; wb[0] = f2bf(w0); wb[1] = f2bf(w1); wb[2] = f2bf(w2); wb[3] = f2bf(w3);
    *(u16x4*)(wbf + (long long)row * 1024 + tid * 4) = wb;
}

// ---------------------------------------------------------------------------
// context = weights @ enc  (per batch: [128,1024] = [128x1024(s)] @ [1024(s),1024(i)])
// A = bf16 weights (k-contiguous); B = enc fp32, transposed+bf16-converted via LDS.
// Writes bf16 directly into cat[:, 0:1024] (ldc = 2048). grid (1,8,64).
// ---------------------------------------------------------------------------
__global__ __launch_bounds__(256) void gemm_ctx(
    const unsigned short* __restrict__ Wb, const float* __restrict__ enc,
    unsigned short* __restrict__ cat)
{
    const int bz = blockIdx.z;
    const int n0 = blockIdx.y * 128;
    const unsigned short* Ab = Wb + (long long)bz * 128 * 1024;
    const float* Bb = enc + (long long)bz * 1024 * 1024;

    __shared__ unsigned short Ah[128*LSTR], Bh[128*LSTR];

    const int tid = threadIdx.x, lane = tid & 63, wave = tid >> 6;
    const int wm = (wave & 1) * 64, wn = (wave >> 1) * 64;
    const int fr = lane & 15, kq = lane >> 4;

    f32x4 zero = {0.f, 0.f, 0.f, 0.f};
    f32x4 acc[4][4];
    #pragma unroll
    for (int i = 0; i < 4; i++)
        #pragma unroll
        for (int j = 0; j < 4; j++) acc[i][j] = zero;

    for (int k0 = 0; k0 < 1024; k0 += 32) {
        #pragma unroll
        for (int i = 0; i < 2; i++) {        // A: 128x32 bf16, 16B loads
            int f = i * 256 + tid;
            int row = f >> 2, c8 = (f & 3) * 8;
            *(short8*)&Ah[row*LSTR + c8] = *(const short8*)(Ab + (long long)row*1024 + k0 + c8);
        }
        #pragma unroll
        for (int jj = 0; jj < 16; jj++) {    // B: 32(k)x128(n) fp32 -> Bh[n][k] bf16
            int linear = jj * 256 + tid;
            int kr = linear >> 7, n = linear & 127;
            Bh[n*LSTR + kr] = f2bf(Bb[(long long)(k0 + kr) * 1024 + n0 + n]);
        }
        __syncthreads();

        short8 fa[4], fb[4];
        #pragma unroll
        for (int fi = 0; fi < 4; fi++) {
            fa[fi] = *(const short8*)&Ah[(wm + fi*16 + fr)*LSTR + kq*8];
            fb[fi] = *(const short8*)&Bh[(wn + fi*16 + fr)*LSTR + kq*8];
        }
        #pragma unroll
        for (int fi = 0; fi < 4; fi++)
            #pragma unroll
            for (int fj = 0; fj < 4; fj++)
                acc[fi][fj] = __builtin_amdgcn_mfma_f32_16x16x32_bf16(fa[fi], fb[fj], acc[fi][fj], 0, 0, 0);
        __syncthreads();
    }

    #pragma unroll
    for (int fi = 0; fi < 4; fi++) {
        int rb = bz * 128 + wm + fi*16 + kq*4;
        #pragma unroll
        for (int fj = 0; fj < 4; fj++) {
            int col = n0 + wn + fj*16 + fr;
            #pragma unroll
            for (int j = 0; j < 4; j++)
                cat[(long long)(rb + j) * 2048 + col] = f2bf(acc[fi][fj][j]);
        }
    }
}

// dec fp32 -> cat[:, 1024:2048] bf16
__global__ __launch_bounds__(256) void pack_dec(
    const float* __restrict__ dec, unsigned short* __restrict__ cat)
{
    long long i = (long long)blockIdx.x * 256 + threadIdx.x;  // float4 id
    float4 x = *(const float4*)(dec + i * 4);
    long long e = i * 4;
    int m = (int)(e >> 10), c = (int)(e & 1023);
    u16x4 h; h[0] = f2bf(x.x); h[1] = f2bf(x.y); h[2] = f2bf(x.z); h[3] = f2bf(x.w);
    *(u16x4*)(cat + (long long)m * 2048 + 1024 + c) = h;
}

// ---------------------------------------------------------------------------
// out = tanh(cat @ W_out^T + b). A = cat bf16 [8192,2048]; B = W_out fp32
// [1024,2048] converted on the fly. grid (64,8,1).
// ---------------------------------------------------------------------------
__global__ __launch_bounds__(256) void gemm_out(
    const unsigned short* __restrict__ cat, const float* __restrict__ W,
    const float* __restrict__ bias, float* __restrict__ out)
{
    const int m0 = blockIdx.x * 128, n0 = blockIdx.y * 128;

    __shared__ unsigned short Ah[128*LSTR], Bh[128*LSTR];

    const int tid = threadIdx.x, lane = tid & 63, wave = tid >> 6;
    const int wm = (wave & 1) * 64, wn = (wave >> 1) * 64;
    const int fr = lane & 15, kq = lane >> 4;

    f32x4 zero = {0.f, 0.f, 0.f, 0.f};
    f32x4 acc[4][4];
    #pragma unroll
    for (int i = 0; i < 4; i++)
        #pragma unroll
        for (int j = 0; j < 4; j++) acc[i][j] = zero;

    for (int k0 = 0; k0 < 2048; k0 += 32) {
        #pragma unroll
        for (int i = 0; i < 2; i++) {        // A: bf16 16B loads
            int f = i * 256 + tid;
            int row = f >> 2, c8 = (f & 3) * 8;
            *(short8*)&Ah[row*LSTR + c8] = *(const short8*)(cat + (long long)(m0 + row)*2048 + k0 + c8);
        }
        #pragma unroll
        for (int i = 0; i < 4; i++) {        // B: fp32 -> bf16
            int f = i * 256 + tid;
            int row = f >> 3, c4 = (f & 7) * 4;
            float4 b4 = *(const float4*)(W + (long long)(n0 + row)*2048 + k0 + c4);
            u16x4 bh; bh[0] = f2bf(b4.x); bh[1] = f2bf(b4.y); bh[2] = f2bf(b4.z); bh[3] = f2bf(b4.w);
            *(u16x4*)&Bh[row*LSTR + c4] = bh;
        }
        __syncthreads();

        short8 fa[4], fb[4];
        #pragma unroll
        for (int fi = 0; fi < 4; fi++) {
            fa[fi] = *(const short8*)&Ah[(wm + fi*16 + fr)*LSTR + kq*8];
            fb[fi] = *(const short8*)&Bh[(wn + fi*16 + fr)*LSTR + kq*8];
        }
        #pragma unroll
        for (int fi = 0; fi < 4; fi++)
            #pragma unroll
            for (int fj = 0; fj < 4; fj++)
                acc[fi][fj] = __builtin_amdgcn_mfma_f32_16x16x32_bf16(fa[fi], fb[fj], acc[fi][fj], 0, 0, 0);
        __syncthreads();
    }

    #pragma unroll
    for (int fi = 0; fi < 4; fi++) {
        int rb = m0 + wm + fi*16 + kq*4;
        #pragma unroll
        for (int fj = 0; fj < 4; fj++) {
            int col = n0 + wn + fj*16 + fr;
            float bb = bias[col];
            #pragma unroll
            for (int j = 0; j < 4; j++)
                out[(long long)(rb + j) * 1024 + col] = tanhf(acc[fi][fj][j] + bb);
        }
    }
}

extern "C" void kernel_launch(void* const* d_in, const int* in_sizes, int n_in,
                              void* d_out, int out_size, void* d_ws, size_t ws_size,
                              hipStream_t stream) {
    const float* dec    = (const float*)d_in[0];   // [64,128,1024]
    const float* enc    = (const float*)d_in[1];   // [64,1024,1024]
    const int*   mask   = (const int*)d_in[2];     // [64,1024] bool->int
    const float* W_attn = (const float*)d_in[3];   // [1024,1024]
    const float* W_out  = (const float*)d_in[4];   // [1024,2048]
    const float* b_out  = (const float*)d_in[5];   // [1024]

    float* out_attn = (float*)d_out;               // [8192,1024]
    float* weights  = out_attn + 8388608;          // [8192,1024] (also scores scratch)

    char* ws = (char*)d_ws;
    float*          q_proj = (float*)ws;                         // 32 MB
    unsigned short* w_bf   = (unsigned short*)(ws + (32 << 20)); // 16 MB
    unsigned short* cat    = (unsigned short*)(ws + (48 << 20)); // 32 MB
    // total ws use: 80 MB

    dim3 blk(256);

    // 1. q_proj = dec @ W_attn^T   [8192,1024], split-bf16 fp32-accurate
    gemm_bt_split<<<dim3(64, 8, 1), blk, 0, stream>>>(
        dec, W_attn, q_proj, 1024, 1024, 0, 0, 0);

    // 2. scores = q_proj @ enc^T per batch -> weights region (pre-softmax)
    gemm_bt_split<<<dim3(1, 8, 64), blk, 0, stream>>>(
        q_proj, enc, weights, 1024, 1024, 128LL*1024, 1024LL*1024, 128LL*1024);

    // 3. masked softmax in place (+ bf16 copy for context GEMM)
    softmax_mask<<<dim3(8192), blk, 0, stream>>>(weights, mask, w_bf);

    // 3b. dec -> cat[:,1024:2048] bf16
    pack_dec<<<dim3(8192), blk, 0, stream>>>(dec, cat);

    // 4. context = weights @ enc -> cat[:,0:1024] bf16
    gemm_ctx<<<dim3(1, 8, 64), blk, 0, stream>>>(w_bf, enc, cat);

    // 5. attn_outputs = tanh(cat @ W_out^T + b_out)
    gemm_out<<<dim3(64, 8, 1), blk, 0, stream>>>(cat, W_out, b_out, out_attn);
}

// Round 2
// 647.336 us; speedup vs baseline: 1.0494x; 1.0494x over previous
//
#include <hip/hip_runtime.h>
#include <math.h>

// Attention_28200755265553: B=64,T=128,S=1024,IN=OUT=1024,CAT=2048
// Pipeline: pre-split fp32->hi/lo bf16 (Ootomo 3-MFMA for the score path),
// all GEMM staging via global_load_lds width=16 where operands are bf16.

typedef __attribute__((ext_vector_type(8))) short short8;
typedef __attribute__((ext_vector_type(4))) float f32x4;
typedef __attribute__((ext_vector_type(4))) unsigned short u16x4;

__device__ __forceinline__ unsigned short f2bf(float x) {
    union { float f; unsigned int u; } v; v.f = x;
    unsigned int u = v.u + (0x7fffu + ((v.u >> 16) & 1u)); // RNE
    return (unsigned short)(u >> 16);
}
__device__ __forceinline__ float bf2f(unsigned short h) {
    union { unsigned int u; float f; } v; v.u = ((unsigned int)h) << 16;
    return v.f;
}
// async global->LDS, 16B per lane; lds ptr must be base + lane*16 (linear in tid)
__device__ __forceinline__ void g2lds16(const void* g, void* l) {
    __builtin_amdgcn_global_load_lds(
        (const __attribute__((address_space(1))) void*)g,
        (__attribute__((address_space(3))) void*)l, 16, 0, 0);
}

// ---------------------------------------------------------------------------
// elementwise pre-passes
// ---------------------------------------------------------------------------
__global__ __launch_bounds__(256) void split_f32(
    const float* __restrict__ src, unsigned short* __restrict__ hi,
    unsigned short* __restrict__ lo)
{
    long long i = (long long)blockIdx.x * 256 + threadIdx.x;
    float4 x = *(const float4*)(src + i * 4);
    float v[4] = {x.x, x.y, x.z, x.w};
    u16x4 h, l;
    #pragma unroll
    for (int j = 0; j < 4; j++) {
        h[j] = f2bf(v[j]);
        l[j] = f2bf(v[j] - bf2f(h[j]));
    }
    *(u16x4*)(hi + i * 4) = h;
    *(u16x4*)(lo + i * 4) = l;
}

__global__ __launch_bounds__(256) void cvt_f32(
    const float* __restrict__ src, unsigned short* __restrict__ dst)
{
    long long i = (long long)blockIdx.x * 256 + threadIdx.x;
    float4 x = *(const float4*)(src + i * 4);
    u16x4 h; h[0] = f2bf(x.x); h[1] = f2bf(x.y); h[2] = f2bf(x.z); h[3] = f2bf(x.w);
    *(u16x4*)(dst + i * 4) = h;
}

// ---------------------------------------------------------------------------
// q_proj: C = dec @ W_attn^T, split-bf16 (3 MFMA), K=N=1024.
// All four tiles staged via global_load_lds. Output written as hi/lo bf16.
// grid (64,8,1), 256 thr.
// ---------------------------------------------------------------------------
__global__ __launch_bounds__(256) void gemm3_qproj(
    const unsigned short* __restrict__ Ahi, const unsigned short* __restrict__ Alo,
    const unsigned short* __restrict__ Bhi, const unsigned short* __restrict__ Blo,
    unsigned short* __restrict__ Chi, unsigned short* __restrict__ Clo)
{
    const int m0 = blockIdx.x * 128, n0 = blockIdx.y * 128;
    __shared__ __align__(16) unsigned short Ah[128*32], Al[128*32], Bh[128*32], Bl[128*32];

    const int tid = threadIdx.x, lane = tid & 63, wave = tid >> 6;
    const int wm = (wave & 1) * 64, wn = (wave >> 1) * 64;
    const int fr = lane & 15, kq = lane >> 4;
    const int row0 = tid >> 2, c80 = (tid & 3) * 8;   // staging unit: 16B = 8 bf16

    f32x4 zero = {0.f, 0.f, 0.f, 0.f};
    f32x4 acc[4][4];
    #pragma unroll
    for (int i = 0; i < 4; i++)
        #pragma unroll
        for (int j = 0; j < 4; j++) acc[i][j] = zero;

    for (int k0 = 0; k0 < 1024; k0 += 32) {
        const unsigned short* pa = Ahi + (long long)(m0 + row0) * 1024 + k0 + c80;
        const unsigned short* pl = Alo + (long long)(m0 + row0) * 1024 + k0 + c80;
        const unsigned short* pb = Bhi + (long long)(n0 + row0) * 1024 + k0 + c80;
        const unsigned short* pm = Blo + (long long)(n0 + row0) * 1024 + k0 + c80;
        g2lds16(pa,            &Ah[tid*8]);
        g2lds16(pa + 64*1024,  &Ah[tid*8 + 2048]);
        g2lds16(pl,            &Al[tid*8]);
        g2lds16(pl + 64*1024,  &Al[tid*8 + 2048]);
        g2lds16(pb,            &Bh[tid*8]);
        g2lds16(pb + 64*1024,  &Bh[tid*8 + 2048]);
        g2lds16(pm,            &Bl[tid*8]);
        g2lds16(pm + 64*1024,  &Bl[tid*8 + 2048]);
        __syncthreads();

        short8 fah[4], fal[4], fbh[4], fbl[4];
        #pragma unroll
        for (int fi = 0; fi < 4; fi++) {
            fah[fi] = *(const short8*)&Ah[(wm + fi*16 + fr)*32 + kq*8];
            fal[fi] = *(const short8*)&Al[(wm + fi*16 + fr)*32 + kq*8];
            fbh[fi] = *(const short8*)&Bh[(wn + fi*16 + fr)*32 + kq*8];
            fbl[fi] = *(const short8*)&Bl[(wn + fi*16 + fr)*32 + kq*8];
        }
        #pragma unroll
        for (int fi = 0; fi < 4; fi++)
            #pragma unroll
            for (int fj = 0; fj < 4; fj++) {
                acc[fi][fj] = __builtin_amdgcn_mfma_f32_16x16x32_bf16(fah[fi], fbh[fj], acc[fi][fj], 0, 0, 0);
                acc[fi][fj] = __builtin_amdgcn_mfma_f32_16x16x32_bf16(fah[fi], fbl[fj], acc[fi][fj], 0, 0, 0);
                acc[fi][fj] = __builtin_amdgcn_mfma_f32_16x16x32_bf16(fal[fi], fbh[fj], acc[fi][fj], 0, 0, 0);
            }
        __syncthreads();
    }

    #pragma unroll
    for (int fi = 0; fi < 4; fi++) {
        int rb = m0 + wm + fi*16 + kq*4;
        #pragma unroll
        for (int fj = 0; fj < 4; fj++) {
            int col = n0 + wn + fj*16 + fr;
            #pragma unroll
            for (int j = 0; j < 4; j++) {
                float x = acc[fi][fj][j];
                unsigned short h = f2bf(x);
                Chi[(long long)(rb + j) * 1024 + col] = h;
                Clo[(long long)(rb + j) * 1024 + col] = f2bf(x - bf2f(h));
            }
        }
    }
}

// ---------------------------------------------------------------------------
// scores: per batch C = q @ enc^T, split-bf16 (3 MFMA). A via global_load_lds
// from pre-split q; B (enc fp32) split on the fly (each element touched once).
// grid (1,8,64).
// ---------------------------------------------------------------------------
__global__ __launch_bounds__(256) void gemm3_scores(
    const unsigned short* __restrict__ Qhi, const unsigned short* __restrict__ Qlo,
    const float* __restrict__ enc, float* __restrict__ C)
{
    const int bz = blockIdx.z, n0 = blockIdx.y * 128;
    const unsigned short* Ahb = Qhi + (long long)bz * 128 * 1024;
    const unsigned short* Alb = Qlo + (long long)bz * 128 * 1024;
    const float* Bb = enc + (long long)bz * 1024 * 1024;
    float* Cb = C + (long long)bz * 128 * 1024;

    __shared__ __align__(16) unsigned short Ah[128*32], Al[128*32], Bh[128*32], Bl[128*32];

    const int tid = threadIdx.x, lane = tid & 63, wave = tid >> 6;
    const int wm = (wave & 1) * 64, wn = (wave >> 1) * 64;
    const int fr = lane & 15, kq = lane >> 4;
    const int row0 = tid >> 2, c80 = (tid & 3) * 8;

    f32x4 zero = {0.f, 0.f, 0.f, 0.f};
    f32x4 acc[4][4];
    #pragma unroll
    for (int i = 0; i < 4; i++)
        #pragma unroll
        for (int j = 0; j < 4; j++) acc[i][j] = zero;

    for (int k0 = 0; k0 < 1024; k0 += 32) {
        const unsigned short* pa = Ahb + (long long)row0 * 1024 + k0 + c80;
        const unsigned short* pl = Alb + (long long)row0 * 1024 + k0 + c80;
        g2lds16(pa,           &Ah[tid*8]);
        g2lds16(pa + 64*1024, &Ah[tid*8 + 2048]);
        g2lds16(pl,           &Al[tid*8]);
        g2lds16(pl + 64*1024, &Al[tid*8 + 2048]);

        // B: 128(n) x 32(k) fp32 -> split bf16; linear LDS writes (bank-balanced)
        #pragma unroll
        for (int i = 0; i < 4; i++) {
            int u = i * 256 + tid;
            int row = u >> 3, c4 = (u & 7) * 4;
            float4 b4 = *(const float4*)(Bb + (long long)(n0 + row) * 1024 + k0 + c4);
            float bv[4] = {b4.x, b4.y, b4.z, b4.w};
            u16x4 hh, ll;
            #pragma unroll
            for (int j = 0; j < 4; j++) {
                hh[j] = f2bf(bv[j]);
                ll[j] = f2bf(bv[j] - bf2f(hh[j]));
            }
            *(u16x4*)&Bh[row*32 + c4] = hh;
            *(u16x4*)&Bl[row*32 + c4] = ll;
        }
        __syncthreads();

        short8 fah[4], fal[4], fbh[4], fbl[4];
        #pragma unroll
        for (int fi = 0; fi < 4; fi++) {
            fah[fi] = *(const short8*)&Ah[(wm + fi*16 + fr)*32 + kq*8];
            fal[fi] = *(const short8*)&Al[(wm + fi*16 + fr)*32 + kq*8];
            fbh[fi] = *(const short8*)&Bh[(wn + fi*16 + fr)*32 + kq*8];
            fbl[fi] = *(const short8*)&Bl[(wn + fi*16 + fr)*32 + kq*8];
        }
        #pragma unroll
        for (int fi = 0; fi < 4; fi++)
            #pragma unroll
            for (int fj = 0; fj < 4; fj++) {
                acc[fi][fj] = __builtin_amdgcn_mfma_f32_16x16x32_bf16(fah[fi], fbh[fj], acc[fi][fj], 0, 0, 0);
                acc[fi][fj] = __builtin_amdgcn_mfma_f32_16x16x32_bf16(fah[fi], fbl[fj], acc[fi][fj], 0, 0, 0);
                acc[fi][fj] = __builtin_amdgcn_mfma_f32_16x16x32_bf16(fal[fi], fbh[fj], acc[fi][fj], 0, 0, 0);
            }
        __syncthreads();
    }

    #pragma unroll
    for (int fi = 0; fi < 4; fi++) {
        int rb = wm + fi*16 + kq*4;
        #pragma unroll
        for (int fj = 0; fj < 4; fj++) {
            int col = n0 + wn + fj*16 + fr;
            #pragma unroll
            for (int j = 0; j < 4; j++)
                Cb[(long long)(rb + j) * 1024 + col] = acc[fi][fj][j];
        }
    }
}

// ---------------------------------------------------------------------------
// masked softmax over S=1024 (fp32 weights in d_out + bf16 copy for ctx GEMM)
// ---------------------------------------------------------------------------
__global__ __launch_bounds__(256) void softmax_mask(
    float* __restrict__ sw, const int* __restrict__ mask,
    unsigned short* __restrict__ wbf)
{
    const int row = blockIdx.x;          // b*128 + t
    const int b = row >> 7;
    const int tid = threadIdx.x, lane = tid & 63, wave = tid >> 6;
    float* sr = sw + (long long)row * 1024;
    const int* mr = mask + (long long)b * 1024;

    float4 x = *(const float4*)(sr + tid * 4);
    int4  mk = *(const int4*)(mr + tid * 4);
    float v0 = mk.x ? -INFINITY : x.x;
    float v1 = mk.y ? -INFINITY : x.y;
    float v2 = mk.z ? -INFINITY : x.z;
    float v3 = mk.w ? -INFINITY : x.w;

    float mx = fmaxf(fmaxf(v0, v1), fmaxf(v2, v3));
    #pragma unroll
    for (int off = 32; off; off >>= 1) mx = fmaxf(mx, __shfl_xor(mx, off));
    __shared__ float redm[4], reds[4];
    if (lane == 0) redm[wave] = mx;
    __syncthreads();
    mx = fmaxf(fmaxf(redm[0], redm[1]), fmaxf(redm[2], redm[3]));

    float p0 = __expf(v0 - mx), p1 = __expf(v1 - mx);
    float p2 = __expf(v2 - mx), p3 = __expf(v3 - mx);
    float s = (p0 + p1) + (p2 + p3);
    #pragma unroll
    for (int off = 32; off; off >>= 1) s += __shfl_xor(s, off);
    if (lane == 0) reds[wave] = s;
    __syncthreads();
    s = (reds[0] + reds[1]) + (reds[2] + reds[3]);
    float inv = 1.0f / s;

    float w0 = p0*inv, w1 = p1*inv, w2 = p2*inv, w3 = p3*inv;
    float4 w4; w4.x = w0; w4.y = w1; w4.z = w2; w4.w = w3;
    *(float4*)(sr + tid * 4) = w4;
    u16x4 wb; wb[0] = f2bf(w0); wb[1] = f2bf(w1); wb[2] = f2bf(w2); wb[3] = f2bf(w3);
    *(u16x4*)(wbf + (long long)row * 1024 + tid * 4) = wb;
}

// ---------------------------------------------------------------------------
// ctx = weights @ enc per batch. A (w_bf) via global_load_lds; B = enc fp32
// transposed via 4x4 register blocks -> stride-40 padded LDS (bank-balanced).
// Output bf16 ctx. grid (1,8,64).
// ---------------------------------------------------------------------------
#define BSTR 40
__global__ __launch_bounds__(256) void gemm_ctx(
    const unsigned short* __restrict__ Wb, const float* __restrict__ enc,
    unsigned short* __restrict__ ctx)
{
    const int bz = blockIdx.z, n0 = blockIdx.y * 128;
    const unsigned short* Ab = Wb + (long long)bz * 128 * 1024;
    const float* Bb = enc + (long long)bz * 1024 * 1024;

    __shared__ __align__(16) unsigned short Ah[128*32];
    __shared__ __align__(16) unsigned short Bt[128*BSTR];

    const int tid = threadIdx.x, lane = tid & 63, wave = tid >> 6;
    const int wm = (wave & 1) * 64, wn = (wave >> 1) * 64;
    const int fr = lane & 15, kq = lane >> 4;
    const int row0 = tid >> 2, c80 = (tid & 3) * 8;
    const int kb = tid & 7, nb = tid >> 3;   // transpose mapping (bank-balanced)

    f32x4 zero = {0.f, 0.f, 0.f, 0.f};
    f32x4 acc[4][4];
    #pragma unroll
    for (int i = 0; i < 4; i++)
        #pragma unroll
        for (int j = 0; j < 4; j++) acc[i][j] = zero;

    for (int k0 = 0; k0 < 1024; k0 += 32) {
        const unsigned short* pa = Ab + (long long)row0 * 1024 + k0 + c80;
        g2lds16(pa,           &Ah[tid*8]);
        g2lds16(pa + 64*1024, &Ah[tid*8 + 2048]);

        // B: read 4x4 fp32 block (rows k, cols n), transpose to Bt[n][k] bf16
        float4 r0 = *(const float4*)(Bb + (long long)(k0 + kb*4 + 0) * 1024 + n0 + nb*4);
        float4 r1 = *(const float4*)(Bb + (long long)(k0 + kb*4 + 1) * 1024 + n0 + nb*4);
        float4 r2 = *(const float4*)(Bb + (long long)(k0 + kb*4 + 2) * 1024 + n0 + nb*4);
        float4 r3 = *(const float4*)(Bb + (long long)(k0 + kb*4 + 3) * 1024 + n0 + nb*4);
        u16x4 v;
        v[0] = f2bf(r0.x); v[1] = f2bf(r1.x); v[2] = f2bf(r2.x); v[3] = f2bf(r3.x);
        *(u16x4*)&Bt[(nb*4 + 0)*BSTR + kb*4] = v;
        v[0] = f2bf(r0.y); v[1] = f2bf(r1.y); v[2] = f2bf(r2.y); v[3] = f2bf(r3.y);
        *(u16x4*)&Bt[(nb*4 + 1)*BSTR + kb*4] = v;
        v[0] = f2bf(r0.z); v[1] = f2bf(r1.z); v[2] = f2bf(r2.z); v[3] = f2bf(r3.z);
        *(u16x4*)&Bt[(nb*4 + 2)*BSTR + kb*4] = v;
        v[0] = f2bf(r0.w); v[1] = f2bf(r1.w); v[2] = f2bf(r2.w); v[3] = f2bf(r3.w);
        *(u16x4*)&Bt[(nb*4 + 3)*BSTR + kb*4] = v;
        __syncthreads();

        short8 fa[4], fb[4];
        #pragma unroll
        for (int fi = 0; fi < 4; fi++) {
            fa[fi] = *(const short8*)&Ah[(wm + fi*16 + fr)*32 + kq*8];
            fb[fi] = *(const short8*)&Bt[(wn + fi*16 + fr)*BSTR + kq*8];
        }
        #pragma unroll
        for (int fi = 0; fi < 4; fi++)
            #pragma unroll
            for (int fj = 0; fj < 4; fj++)
                acc[fi][fj] = __builtin_amdgcn_mfma_f32_16x16x32_bf16(fa[fi], fb[fj], acc[fi][fj], 0, 0, 0);
        __syncthreads();
    }

    #pragma unroll
    for (int fi = 0; fi < 4; fi++) {
        int rb = bz * 128 + wm + fi*16 + kq*4;
        #pragma unroll
        for (int fj = 0; fj < 4; fj++) {
            int col = n0 + wn + fj*16 + fr;
            #pragma unroll
            for (int j = 0; j < 4; j++)
                ctx[(long long)(rb + j) * 1024 + col] = f2bf(acc[fi][fj][j]);
        }
    }
}

// ---------------------------------------------------------------------------
// out = tanh([ctx|dec] @ W_out^T + b). A pointer switches at k=1024 (no cat
// materialization). All staging via global_load_lds. grid (64,8,1).
// ---------------------------------------------------------------------------
__global__ __launch_bounds__(256) void gemm_out(
    const unsigned short* __restrict__ ctx, const unsigned short* __restrict__ dech,
    const unsigned short* __restrict__ Wb, const float* __restrict__ bias,
    float* __restrict__ out)
{
    const int m0 = blockIdx.x * 128, n0 = blockIdx.y * 128;
    __shared__ __align__(16) unsigned short Ah[128*32], Bh[128*32];

    const int tid = threadIdx.x, lane = tid & 63, wave = tid >> 6;
    const int wm = (wave & 1) * 64, wn = (wave >> 1) * 64;
    const int fr = lane & 15, kq = lane >> 4;
    const int row0 = tid >> 2, c80 = (tid & 3) * 8;

    f32x4 zero = {0.f, 0.f, 0.f, 0.f};
    f32x4 acc[4][4];
    #pragma unroll
    for (int i = 0; i < 4; i++)
        #pragma unroll
        for (int j = 0; j < 4; j++) acc[i][j] = zero;

    for (int k0 = 0; k0 < 2048; k0 += 32) {
        const unsigned short* As = (k0 < 1024) ? ctx : dech;
        int kk = k0 & 1023;
        const unsigned short* pa = As + (long long)(m0 + row0) * 1024 + kk + c80;
        const unsigned short* pb = Wb + (long long)(n0 + row0) * 2048 + k0 + c80;
        g2lds16(pa,           &Ah[tid*8]);
        g2lds16(pa + 64*1024, &Ah[tid*8 + 2048]);
        g2lds16(pb,           &Bh[tid*8]);
        g2lds16(pb + 64*2048, &Bh[tid*8 + 2048]);
        __syncthreads();

        short8 fa[4], fb[4];
        #pragma unroll
        for (int fi = 0; fi < 4; fi++) {
            fa[fi] = *(const short8*)&Ah[(wm + fi*16 + fr)*32 + kq*8];
            fb[fi] = *(const short8*)&Bh[(wn + fi*16 + fr)*32 + kq*8];
        }
        #pragma unroll
        for (int fi = 0; fi < 4; fi++)
            #pragma unroll
            for (int fj = 0; fj < 4; fj++)
                acc[fi][fj] = __builtin_amdgcn_mfma_f32_16x16x32_bf16(fa[fi], fb[fj], acc[fi][fj], 0, 0, 0);
        __syncthreads();
    }

    #pragma unroll
    for (int fi = 0; fi < 4; fi++) {
        int rb = m0 + wm + fi*16 + kq*4;
        #pragma unroll
        for (int fj = 0; fj < 4; fj++) {
            int col = n0 + wn + fj*16 + fr;
            float bb = bias[col];
            #pragma unroll
            for (int j = 0; j < 4; j++)
                out[(long long)(rb + j) * 1024 + col] = tanhf(acc[fi][fj][j] + bb);
        }
    }
}

extern "C" void kernel_launch(void* const* d_in, const int* in_sizes, int n_in,
                              void* d_out, int out_size, void* d_ws, size_t ws_size,
                              hipStream_t stream) {
    const float* dec    = (const float*)d_in[0];   // [64,128,1024]
    const float* enc    = (const float*)d_in[1];   // [64,1024,1024]
    const int*   mask   = (const int*)d_in[2];     // [64,1024]
    const float* W_attn = (const float*)d_in[3];   // [1024,1024]
    const float* W_out  = (const float*)d_in[4];   // [1024,2048]
    const float* b_out  = (const float*)d_in[5];   // [1024]

    float* out_attn = (float*)d_out;               // [8192,1024]
    float* weights  = out_attn + 8388608;          // [8192,1024] scores->softmax in place

    char* ws = (char*)d_ws;
    unsigned short* dec_hi = (unsigned short*)(ws);              // 16 MB
    unsigned short* dec_lo = (unsigned short*)(ws + (16 << 20)); // 16 MB
    unsigned short* wa_hi  = (unsigned short*)(ws + (32 << 20)); //  2 MB
    unsigned short* wa_lo  = (unsigned short*)(ws + (34 << 20)); //  2 MB
    unsigned short* wout_b = (unsigned short*)(ws + (36 << 20)); //  4 MB
    unsigned short* q_hi   = (unsigned short*)(ws + (40 << 20)); // 16 MB
    unsigned short* q_lo   = (unsigned short*)(ws + (56 << 20)); // 16 MB
    unsigned short* w_bf   = (unsigned short*)(ws + (72 << 20)); // 16 MB
    unsigned short* ctx_bf = (unsigned short*)(ws + (88 << 20)); // 16 MB -> 104 MB total

    dim3 blk(256);

    split_f32<<<dim3(8192), blk, 0, stream>>>(dec, dec_hi, dec_lo);
    split_f32<<<dim3(1024), blk, 0, stream>>>(W_attn, wa_hi, wa_lo);
    cvt_f32<<<dim3(2048), blk, 0, stream>>>(W_out, wout_b);

    gemm3_qproj<<<dim3(64, 8, 1), blk, 0, stream>>>(dec_hi, dec_lo, wa_hi, wa_lo, q_hi, q_lo);
    gemm3_scores<<<dim3(1, 8, 64), blk, 0, stream>>>(q_hi, q_lo, enc, weights);
    softmax_mask<<<dim3(8192), blk, 0, stream>>>(weights, mask, w_bf);
    gemm_ctx<<<dim3(1, 8, 64), blk, 0, stream>>>(w_bf, enc, ctx_bf);
    gemm_out<<<dim3(64, 8, 1), blk, 0, stream>>>(ctx_bf, dec_hi, wout_b, b_out, out_attn);
}

// Round 3
// 642.273 us; speedup vs baseline: 1.0577x; 1.0079x over previous
//
#include <hip/hip_runtime.h>
#include <math.h>

// Attention_28200755265553: B=64,T=128,S=1024,IN=OUT=1024,CAT=2048
// Pipeline: RTZ hi/lo bf16 split (exact hi, lo=residual) for the score path
// (Ootomo 3-MFMA); v_perm packing makes every fp32->bf16 conversion ~1 op.
// All k-contiguous bf16 staging via global_load_lds width=16.

typedef __attribute__((ext_vector_type(8))) short short8;
typedef __attribute__((ext_vector_type(4))) float f32x4;
typedef __attribute__((ext_vector_type(4))) unsigned short u16x4;

__device__ __forceinline__ unsigned int fbits(float x) {
    union { float f; unsigned int u; } v; v.f = x; return v.u;
}
__device__ __forceinline__ float asfloat(unsigned int u) {
    union { unsigned int u; float f; } v; v.u = u; return v.f;
}
// truncate to bf16-representable fp32 (RTZ): keep top 16 bits
__device__ __forceinline__ float truncbf(float x) { return asfloat(fbits(x) & 0xffff0000u); }
// pack two floats' top-16 bits: low ushort = bf16_rtz(X), high = bf16_rtz(Y). 1 v_perm.
__device__ __forceinline__ unsigned int pkhi(float X, float Y) {
    return __builtin_amdgcn_perm(fbits(Y), fbits(X), 0x07060302u);
}
// RNE fp32->bf16 (used only in cold paths)
__device__ __forceinline__ unsigned short f2bf(float x) {
    unsigned int u = fbits(x);
    u += 0x7fffu + ((u >> 16) & 1u);
    return (unsigned short)(u >> 16);
}
// async global->LDS, 16B per lane; lds ptr must be linear in tid
__device__ __forceinline__ void g2lds16(const void* g, void* l) {
    __builtin_amdgcn_global_load_lds(
        (const __attribute__((address_space(1))) void*)g,
        (__attribute__((address_space(3))) void*)l, 16, 0, 0);
}

// ---------------------------------------------------------------------------
// elementwise pre-passes
// ---------------------------------------------------------------------------
__global__ __launch_bounds__(256) void split_rtz(
    const float* __restrict__ src, unsigned short* __restrict__ hi,
    unsigned short* __restrict__ lo)
{
    long long i = (long long)blockIdx.x * 256 + threadIdx.x;
    float4 x = *(const float4*)(src + i * 4);
    uint2 h, l;
    h.x = pkhi(x.x, x.y); h.y = pkhi(x.z, x.w);
    float l0 = x.x - truncbf(x.x), l1 = x.y - truncbf(x.y);
    float l2 = x.z - truncbf(x.z), l3 = x.w - truncbf(x.w);
    l.x = pkhi(l0, l1); l.y = pkhi(l2, l3);
    *(uint2*)(hi + i * 4) = h;
    *(uint2*)(lo + i * 4) = l;
}

__global__ __launch_bounds__(256) void cvt_f32(
    const float* __restrict__ src, unsigned short* __restrict__ dst)
{
    long long i = (long long)blockIdx.x * 256 + threadIdx.x;
    float4 x = *(const float4*)(src + i * 4);
    u16x4 h; h[0] = f2bf(x.x); h[1] = f2bf(x.y); h[2] = f2bf(x.z); h[3] = f2bf(x.w);
    *(u16x4*)(dst + i * 4) = h;
}

// ---------------------------------------------------------------------------
// q_proj: C = dec @ W_attn^T, split-bf16 (3 MFMA), K=N=1024. Pure g2lds
// staging; output written as RTZ hi/lo bf16. grid (64,8,1).
// ---------------------------------------------------------------------------
__global__ __launch_bounds__(256) void gemm3_qproj(
    const unsigned short* __restrict__ Ahi, const unsigned short* __restrict__ Alo,
    const unsigned short* __restrict__ Bhi, const unsigned short* __restrict__ Blo,
    unsigned short* __restrict__ Chi, unsigned short* __restrict__ Clo)
{
    const int m0 = blockIdx.x * 128, n0 = blockIdx.y * 128;
    __shared__ __align__(16) unsigned short Ah[128*32], Al[128*32], Bh[128*32], Bl[128*32];

    const int tid = threadIdx.x, lane = tid & 63, wave = tid >> 6;
    const int wm = (wave & 1) * 64, wn = (wave >> 1) * 64;
    const int fr = lane & 15, kq = lane >> 4;
    const int row0 = tid >> 2, c80 = (tid & 3) * 8;

    f32x4 zero = {0.f, 0.f, 0.f, 0.f};
    f32x4 acc[4][4];
    #pragma unroll
    for (int i = 0; i < 4; i++)
        #pragma unroll
        for (int j = 0; j < 4; j++) acc[i][j] = zero;

    for (int k0 = 0; k0 < 1024; k0 += 32) {
        const unsigned short* pa = Ahi + (long long)(m0 + row0) * 1024 + k0 + c80;
        const unsigned short* pl = Alo + (long long)(m0 + row0) * 1024 + k0 + c80;
        const unsigned short* pb = Bhi + (long long)(n0 + row0) * 1024 + k0 + c80;
        const unsigned short* pm = Blo + (long long)(n0 + row0) * 1024 + k0 + c80;
        g2lds16(pa,            &Ah[tid*8]);
        g2lds16(pa + 64*1024,  &Ah[tid*8 + 2048]);
        g2lds16(pl,            &Al[tid*8]);
        g2lds16(pl + 64*1024,  &Al[tid*8 + 2048]);
        g2lds16(pb,            &Bh[tid*8]);
        g2lds16(pb + 64*1024,  &Bh[tid*8 + 2048]);
        g2lds16(pm,            &Bl[tid*8]);
        g2lds16(pm + 64*1024,  &Bl[tid*8 + 2048]);
        __syncthreads();

        short8 fah[4], fal[4], fbh[4], fbl[4];
        #pragma unroll
        for (int fi = 0; fi < 4; fi++) {
            fah[fi] = *(const short8*)&Ah[(wm + fi*16 + fr)*32 + kq*8];
            fal[fi] = *(const short8*)&Al[(wm + fi*16 + fr)*32 + kq*8];
            fbh[fi] = *(const short8*)&Bh[(wn + fi*16 + fr)*32 + kq*8];
            fbl[fi] = *(const short8*)&Bl[(wn + fi*16 + fr)*32 + kq*8];
        }
        #pragma unroll
        for (int fi = 0; fi < 4; fi++)
            #pragma unroll
            for (int fj = 0; fj < 4; fj++) {
                acc[fi][fj] = __builtin_amdgcn_mfma_f32_16x16x32_bf16(fah[fi], fbh[fj], acc[fi][fj], 0, 0, 0);
                acc[fi][fj] = __builtin_amdgcn_mfma_f32_16x16x32_bf16(fah[fi], fbl[fj], acc[fi][fj], 0, 0, 0);
                acc[fi][fj] = __builtin_amdgcn_mfma_f32_16x16x32_bf16(fal[fi], fbh[fj], acc[fi][fj], 0, 0, 0);
            }
        __syncthreads();
    }

    #pragma unroll
    for (int fi = 0; fi < 4; fi++) {
        int rb = m0 + wm + fi*16 + kq*4;
        #pragma unroll
        for (int fj = 0; fj < 4; fj++) {
            int col = n0 + wn + fj*16 + fr;
            #pragma unroll
            for (int j = 0; j < 4; j++) {
                float x = acc[fi][fj][j];
                unsigned int hb = fbits(x) & 0xffff0000u;
                Chi[(long long)(rb + j) * 1024 + col] = (unsigned short)(hb >> 16);
                float l = x - asfloat(hb);
                Clo[(long long)(rb + j) * 1024 + col] = (unsigned short)(fbits(l) >> 16);
            }
        }
    }
}

// ---------------------------------------------------------------------------
// scores: per batch C = q @ enc^T, split-bf16 (3 MFMA). A via g2lds from
// pre-split q; B (enc fp32) RTZ-split on the fly (~3 VALU / 4 elems).
// grid (1,8,64).
// ---------------------------------------------------------------------------
__global__ __launch_bounds__(256) void gemm3_scores(
    const unsigned short* __restrict__ Qhi, const unsigned short* __restrict__ Qlo,
    const float* __restrict__ enc, float* __restrict__ C)
{
    const int bz = blockIdx.z, n0 = blockIdx.y * 128;
    const unsigned short* Ahb = Qhi + (long long)bz * 128 * 1024;
    const unsigned short* Alb = Qlo + (long long)bz * 128 * 1024;
    const float* Bb = enc + (long long)bz * 1024 * 1024;
    float* Cb = C + (long long)bz * 128 * 1024;

    __shared__ __align__(16) unsigned short Ah[128*32], Al[128*32], Bh[128*32], Bl[128*32];

    const int tid = threadIdx.x, lane = tid & 63, wave = tid >> 6;
    const int wm = (wave & 1) * 64, wn = (wave >> 1) * 64;
    const int fr = lane & 15, kq = lane >> 4;
    const int row0 = tid >> 2, c80 = (tid & 3) * 8;

    f32x4 zero = {0.f, 0.f, 0.f, 0.f};
    f32x4 acc[4][4];
    #pragma unroll
    for (int i = 0; i < 4; i++)
        #pragma unroll
        for (int j = 0; j < 4; j++) acc[i][j] = zero;

    for (int k0 = 0; k0 < 1024; k0 += 32) {
        const unsigned short* pa = Ahb + (long long)row0 * 1024 + k0 + c80;
        const unsigned short* pl = Alb + (long long)row0 * 1024 + k0 + c80;
        g2lds16(pa,           &Ah[tid*8]);
        g2lds16(pa + 64*1024, &Ah[tid*8 + 2048]);
        g2lds16(pl,           &Al[tid*8]);
        g2lds16(pl + 64*1024, &Al[tid*8 + 2048]);

        // B: 128(n) x 32(k) fp32 -> RTZ hi/lo bf16
        #pragma unroll
        for (int i = 0; i < 4; i++) {
            int u = i * 256 + tid;
            int row = u >> 3, c4 = (u & 7) * 4;
            float4 b4 = *(const float4*)(Bb + (long long)(n0 + row) * 1024 + k0 + c4);
            uint2 hh, ll;
            hh.x = pkhi(b4.x, b4.y); hh.y = pkhi(b4.z, b4.w);
            float l0 = b4.x - truncbf(b4.x), l1 = b4.y - truncbf(b4.y);
            float l2 = b4.z - truncbf(b4.z), l3 = b4.w - truncbf(b4.w);
            ll.x = pkhi(l0, l1); ll.y = pkhi(l2, l3);
            *(uint2*)&Bh[row*32 + c4] = hh;
            *(uint2*)&Bl[row*32 + c4] = ll;
        }
        __syncthreads();

        short8 fah[4], fal[4], fbh[4], fbl[4];
        #pragma unroll
        for (int fi = 0; fi < 4; fi++) {
            fah[fi] = *(const short8*)&Ah[(wm + fi*16 + fr)*32 + kq*8];
            fal[fi] = *(const short8*)&Al[(wm + fi*16 + fr)*32 + kq*8];
            fbh[fi] = *(const short8*)&Bh[(wn + fi*16 + fr)*32 + kq*8];
            fbl[fi] = *(const short8*)&Bl[(wn + fi*16 + fr)*32 + kq*8];
        }
        #pragma unroll
        for (int fi = 0; fi < 4; fi++)
            #pragma unroll
            for (int fj = 0; fj < 4; fj++) {
                acc[fi][fj] = __builtin_amdgcn_mfma_f32_16x16x32_bf16(fah[fi], fbh[fj], acc[fi][fj], 0, 0, 0);
                acc[fi][fj] = __builtin_amdgcn_mfma_f32_16x16x32_bf16(fah[fi], fbl[fj], acc[fi][fj], 0, 0, 0);
                acc[fi][fj] = __builtin_amdgcn_mfma_f32_16x16x32_bf16(fal[fi], fbh[fj], acc[fi][fj], 0, 0, 0);
            }
        __syncthreads();
    }

    #pragma unroll
    for (int fi = 0; fi < 4; fi++) {
        int rb = wm + fi*16 + kq*4;
        #pragma unroll
        for (int fj = 0; fj < 4; fj++) {
            int col = n0 + wn + fj*16 + fr;
            #pragma unroll
            for (int j = 0; j < 4; j++)
                Cb[(long long)(rb + j) * 1024 + col] = acc[fi][fj][j];
        }
    }
}

// ---------------------------------------------------------------------------
// masked softmax over S=1024 (fp32 weights in d_out + bf16 copy for ctx GEMM)
// ---------------------------------------------------------------------------
__global__ __launch_bounds__(256) void softmax_mask(
    float* __restrict__ sw, const int* __restrict__ mask,
    unsigned short* __restrict__ wbf)
{
    const int row = blockIdx.x;          // b*128 + t
    const int b = row >> 7;
    const int tid = threadIdx.x, lane = tid & 63, wave = tid >> 6;
    float* sr = sw + (long long)row * 1024;
    const int* mr = mask + (long long)b * 1024;

    float4 x = *(const float4*)(sr + tid * 4);
    int4  mk = *(const int4*)(mr + tid * 4);
    float v0 = mk.x ? -INFINITY : x.x;
    float v1 = mk.y ? -INFINITY : x.y;
    float v2 = mk.z ? -INFINITY : x.z;
    float v3 = mk.w ? -INFINITY : x.w;

    float mx = fmaxf(fmaxf(v0, v1), fmaxf(v2, v3));
    #pragma unroll
    for (int off = 32; off; off >>= 1) mx = fmaxf(mx, __shfl_xor(mx, off));
    __shared__ float redm[4], reds[4];
    if (lane == 0) redm[wave] = mx;
    __syncthreads();
    mx = fmaxf(fmaxf(redm[0], redm[1]), fmaxf(redm[2], redm[3]));

    float p0 = __expf(v0 - mx), p1 = __expf(v1 - mx);
    float p2 = __expf(v2 - mx), p3 = __expf(v3 - mx);
    float s = (p0 + p1) + (p2 + p3);
    #pragma unroll
    for (int off = 32; off; off >>= 1) s += __shfl_xor(s, off);
    if (lane == 0) reds[wave] = s;
    __syncthreads();
    s = (reds[0] + reds[1]) + (reds[2] + reds[3]);
    float inv = 1.0f / s;

    float w0 = p0*inv, w1 = p1*inv, w2 = p2*inv, w3 = p3*inv;
    float4 w4; w4.x = w0; w4.y = w1; w4.z = w2; w4.w = w3;
    *(float4*)(sr + tid * 4) = w4;
    u16x4 wb; wb[0] = f2bf(w0); wb[1] = f2bf(w1); wb[2] = f2bf(w2); wb[3] = f2bf(w3);
    *(u16x4*)(wbf + (long long)row * 1024 + tid * 4) = wb;
}

// ---------------------------------------------------------------------------
// ctx = weights @ enc per batch. A (w_bf) via g2lds; B = enc fp32 transposed
// via 4x4 register blocks, RTZ+perm pack (2 VALU / 4 elems). grid (1,8,64).
// ---------------------------------------------------------------------------
#define BSTR 40
__global__ __launch_bounds__(256) void gemm_ctx(
    const unsigned short* __restrict__ Wb, const float* __restrict__ enc,
    unsigned short* __restrict__ ctx)
{
    const int bz = blockIdx.z, n0 = blockIdx.y * 128;
    const unsigned short* Ab = Wb + (long long)bz * 128 * 1024;
    const float* Bb = enc + (long long)bz * 1024 * 1024;

    __shared__ __align__(16) unsigned short Ah[128*32];
    __shared__ __align__(16) unsigned short Bt[128*BSTR];

    const int tid = threadIdx.x, lane = tid & 63, wave = tid >> 6;
    const int wm = (wave & 1) * 64, wn = (wave >> 1) * 64;
    const int fr = lane & 15, kq = lane >> 4;
    const int row0 = tid >> 2, c80 = (tid & 3) * 8;
    const int kb = tid & 7, nb = tid >> 3;

    f32x4 zero = {0.f, 0.f, 0.f, 0.f};
    f32x4 acc[4][4];
    #pragma unroll
    for (int i = 0; i < 4; i++)
        #pragma unroll
        for (int j = 0; j < 4; j++) acc[i][j] = zero;

    for (int k0 = 0; k0 < 1024; k0 += 32) {
        const unsigned short* pa = Ab + (long long)row0 * 1024 + k0 + c80;
        g2lds16(pa,           &Ah[tid*8]);
        g2lds16(pa + 64*1024, &Ah[tid*8 + 2048]);

        // B: 4x4 fp32 block (rows k, cols n) -> Bt[n][k] bf16 via perm packing
        float4 r0 = *(const float4*)(Bb + (long long)(k0 + kb*4 + 0) * 1024 + n0 + nb*4);
        float4 r1 = *(const float4*)(Bb + (long long)(k0 + kb*4 + 1) * 1024 + n0 + nb*4);
        float4 r2 = *(const float4*)(Bb + (long long)(k0 + kb*4 + 2) * 1024 + n0 + nb*4);
        float4 r3 = *(const float4*)(Bb + (long long)(k0 + kb*4 + 3) * 1024 + n0 + nb*4);
        uint2 c;
        c.x = pkhi(r0.x, r1.x); c.y = pkhi(r2.x, r3.x);
        *(uint2*)&Bt[(nb*4 + 0)*BSTR + kb*4] = c;
        c.x = pkhi(r0.y, r1.y); c.y = pkhi(r2.y, r3.y);
        *(uint2*)&Bt[(nb*4 + 1)*BSTR + kb*4] = c;
        c.x = pkhi(r0.z, r1.z); c.y = pkhi(r2.z, r3.z);
        *(uint2*)&Bt[(nb*4 + 2)*BSTR + kb*4] = c;
        c.x = pkhi(r0.w, r1.w); c.y = pkhi(r2.w, r3.w);
        *(uint2*)&Bt[(nb*4 + 3)*BSTR + kb*4] = c;
        __syncthreads();

        short8 fa[4], fb[4];
        #pragma unroll
        for (int fi = 0; fi < 4; fi++) {
            fa[fi] = *(const short8*)&Ah[(wm + fi*16 + fr)*32 + kq*8];
            fb[fi] = *(const short8*)&Bt[(wn + fi*16 + fr)*BSTR + kq*8];
        }
        #pragma unroll
        for (int fi = 0; fi < 4; fi++)
            #pragma unroll
            for (int fj = 0; fj < 4; fj++)
                acc[fi][fj] = __builtin_amdgcn_mfma_f32_16x16x32_bf16(fa[fi], fb[fj], acc[fi][fj], 0, 0, 0);
        __syncthreads();
    }

    #pragma unroll
    for (int fi = 0; fi < 4; fi++) {
        int rb = bz * 128 + wm + fi*16 + kq*4;
        #pragma unroll
        for (int fj = 0; fj < 4; fj++) {
            int col = n0 + wn + fj*16 + fr;
            #pragma unroll
            for (int j = 0; j < 4; j++)
                ctx[(long long)(rb + j) * 1024 + col] = f2bf(acc[fi][fj][j]);
        }
    }
}

// ---------------------------------------------------------------------------
// out = tanh([ctx|dec] @ W_out^T + b). A pointer switches at k=1024. Pure
// g2lds staging. grid (64,8,1).
// ---------------------------------------------------------------------------
__global__ __launch_bounds__(256) void gemm_out(
    const unsigned short* __restrict__ ctx, const unsigned short* __restrict__ dech,
    const unsigned short* __restrict__ Wb, const float* __restrict__ bias,
    float* __restrict__ out)
{
    const int m0 = blockIdx.x * 128, n0 = blockIdx.y * 128;
    __shared__ __align__(16) unsigned short Ah[128*32], Bh[128*32];

    const int tid = threadIdx.x, lane = tid & 63, wave = tid >> 6;
    const int wm = (wave & 1) * 64, wn = (wave >> 1) * 64;
    const int fr = lane & 15, kq = lane >> 4;
    const int row0 = tid >> 2, c80 = (tid & 3) * 8;

    f32x4 zero = {0.f, 0.f, 0.f, 0.f};
    f32x4 acc[4][4];
    #pragma unroll
    for (int i = 0; i < 4; i++)
        #pragma unroll
        for (int j = 0; j < 4; j++) acc[i][j] = zero;

    for (int k0 = 0; k0 < 2048; k0 += 32) {
        const unsigned short* As = (k0 < 1024) ? ctx : dech;
        int kk = k0 & 1023;
        const unsigned short* pa = As + (long long)(m0 + row0) * 1024 + kk + c80;
        const unsigned short* pb = Wb + (long long)(n0 + row0) * 2048 + k0 + c80;
        g2lds16(pa,           &Ah[tid*8]);
        g2lds16(pa + 64*1024, &Ah[tid*8 + 2048]);
        g2lds16(pb,           &Bh[tid*8]);
        g2lds16(pb + 64*2048, &Bh[tid*8 + 2048]);
        __syncthreads();

        short8 fa[4], fb[4];
        #pragma unroll
        for (int fi = 0; fi < 4; fi++) {
            fa[fi] = *(const short8*)&Ah[(wm + fi*16 + fr)*32 + kq*8];
            fb[fi] = *(const short8*)&Bh[(wn + fi*16 + fr)*32 + kq*8];
        }
        #pragma unroll
        for (int fi = 0; fi < 4; fi++)
            #pragma unroll
            for (int fj = 0; fj < 4; fj++)
                acc[fi][fj] = __builtin_amdgcn_mfma_f32_16x16x32_bf16(fa[fi], fb[fj], acc[fi][fj], 0, 0, 0);
        __syncthreads();
    }

    #pragma unroll
    for (int fi = 0; fi < 4; fi++) {
        int rb = m0 + wm + fi*16 + kq*4;
        #pragma unroll
        for (int fj = 0; fj < 4; fj++) {
            int col = n0 + wn + fj*16 + fr;
            float bb = bias[col];
            #pragma unroll
            for (int j = 0; j < 4; j++)
                out[(long long)(rb + j) * 1024 + col] = tanhf(acc[fi][fj][j] + bb);
        }
    }
}

extern "C" void kernel_launch(void* const* d_in, const int* in_sizes, int n_in,
                              void* d_out, int out_size, void* d_ws, size_t ws_size,
                              hipStream_t stream) {
    const float* dec    = (const float*)d_in[0];   // [64,128,1024]
    const float* enc    = (const float*)d_in[1];   // [64,1024,1024]
    const int*   mask   = (const int*)d_in[2];     // [64,1024]
    const float* W_attn = (const float*)d_in[3];   // [1024,1024]
    const float* W_out  = (const float*)d_in[4];   // [1024,2048]
    const float* b_out  = (const float*)d_in[5];   // [1024]

    float* out_attn = (float*)d_out;               // [8192,1024]
    float* weights  = out_attn + 8388608;          // [8192,1024] scores->softmax in place

    char* ws = (char*)d_ws;
    unsigned short* dec_hi = (unsigned short*)(ws);              // 16 MB
    unsigned short* dec_lo = (unsigned short*)(ws + (16 << 20)); // 16 MB
    unsigned short* wa_hi  = (unsigned short*)(ws + (32 << 20)); //  2 MB
    unsigned short* wa_lo  = (unsigned short*)(ws + (34 << 20)); //  2 MB
    unsigned short* wout_b = (unsigned short*)(ws + (36 << 20)); //  4 MB
    unsigned short* q_hi   = (unsigned short*)(ws + (40 << 20)); // 16 MB
    unsigned short* q_lo   = (unsigned short*)(ws + (56 << 20)); // 16 MB
    unsigned short* w_bf   = (unsigned short*)(ws + (72 << 20)); // 16 MB
    unsigned short* ctx_bf = (unsigned short*)(ws + (88 << 20)); // 16 MB -> 104 MB total

    dim3 blk(256);

    split_rtz<<<dim3(8192), blk, 0, stream>>>(dec, dec_hi, dec_lo);
    split_rtz<<<dim3(1024), blk, 0, stream>>>(W_attn, wa_hi, wa_lo);
    cvt_f32<<<dim3(2048), blk, 0, stream>>>(W_out, wout_b);

    gemm3_qproj<<<dim3(64, 8, 1), blk, 0, stream>>>(dec_hi, dec_lo, wa_hi, wa_lo, q_hi, q_lo);
    gemm3_scores<<<dim3(1, 8, 64), blk, 0, stream>>>(q_hi, q_lo, enc, weights);
    softmax_mask<<<dim3(8192), blk, 0, stream>>>(weights, mask, w_bf);
    gemm_ctx<<<dim3(1, 8, 64), blk, 0, stream>>>(w_bf, enc, ctx_bf);
    gemm_out<<<dim3(64, 8, 1), blk, 0, stream>>>(ctx_bf, dec_hi, wout_b, b_out, out_attn);
}